// Round 1
// baseline (512.924 us; speedup 1.0000x reference)
//
#include <hip/hip_runtime.h>

#define N_NODES 50000
#define N_EDGES 1600000
#define DIM 64
#define EDIM 32
#define NUM_GRAPHS 128
#define NUM_CLASSES 10
#define NBIN_PAD 50176            // 196*256 >= N_NODES+1
#define NSCAN_BLK 196
#define EPAD_MAX 2200000          // >= sum(ceil(deg/16)*16)

typedef __attribute__((ext_vector_type(8))) short bf16x8;
typedef __attribute__((ext_vector_type(4))) short short4v;
typedef __attribute__((ext_vector_type(4))) float f32x4;

static __device__ __forceinline__ short f2bf(float f) {
    unsigned u = __builtin_bit_cast(unsigned, f);
    u += 0x7fff + ((u >> 16) & 1);   // round-to-nearest-even
    return (short)(u >> 16);
}
static __device__ __forceinline__ float bf2f(short s) {
    unsigned u = ((unsigned)(unsigned short)s) << 16;
    return __builtin_bit_cast(float, u);
}
// pack 2 f32 -> 2 bf16 in one v_cvt_pk_bf16_f32 (no builtin on gfx950)
static __device__ __forceinline__ int cvt_pk_bf16(float lo, float hi) {
    int r;
    asm("v_cvt_pk_bf16_f32 %0, %1, %2" : "=v"(r) : "v"(lo), "v"(hi));
    return r;
}

__global__ void hist_kernel(const int* __restrict__ dst, int* __restrict__ cnt) {
    int i = blockIdx.x * blockDim.x + threadIdx.x;
    int stride = gridDim.x * blockDim.x;
    for (int e = i; e < N_EDGES; e += stride)
        atomicAdd(&cnt[dst[e]], 1);
}

// Exclusive scan of PADDED degrees (ceil(deg/16)*16) -> pstart.
__global__ void scan_part(const int* __restrict__ cnt, int* __restrict__ pstart,
                          int* __restrict__ partial) {
    __shared__ int sh[256];
    const int b = blockIdx.x, t = threadIdx.x;
    const int i = b * 256 + t;
    int v = ((cnt[i] + 15) >> 4) << 4;
    sh[t] = v;
    __syncthreads();
    #pragma unroll
    for (int off = 1; off < 256; off <<= 1) {
        int add = (t >= off) ? sh[t - off] : 0;
        __syncthreads();
        sh[t] += add;
        __syncthreads();
    }
    pstart[i] = sh[t] - v;
    if (t == 255) partial[b] = sh[t];
}

__global__ void scan_mid(int* __restrict__ partial) {
    __shared__ int sh[256];
    const int t = threadIdx.x;
    int v = (t < NSCAN_BLK) ? partial[t] : 0;
    sh[t] = v;
    __syncthreads();
    #pragma unroll
    for (int off = 1; off < 256; off <<= 1) {
        int add = (t >= off) ? sh[t - off] : 0;
        __syncthreads();
        sh[t] += add;
        __syncthreads();
    }
    if (t < NSCAN_BLK) partial[t] = sh[t] - v;
}

__global__ void scan_add(int* __restrict__ pstart, const int* __restrict__ partial,
                         int* __restrict__ cursor) {
    const int b = blockIdx.x, t = threadIdx.x;
    const int i = b * 256 + t;
    int p = pstart[i] + partial[b];
    pstart[i] = p;
    cursor[i] = p;
}

// scatter: pes[p] = {orig edge id, src node}. Single 8B store per edge
// (halves the randomly-touched 64B sectors vs two 4B stores).
__global__ void scatter_kernel(const int* __restrict__ src, const int* __restrict__ dst,
                               int* __restrict__ cursor, int2* __restrict__ pes) {
    int i = blockIdx.x * blockDim.x + threadIdx.x;
    int stride = gridDim.x * blockDim.x;
    for (int e = i; e < N_EDGES; e += stride) {
        int p = atomicAdd(&cursor[dst[e]], 1);
        int2 r; r.x = e; r.y = src[e];
        pes[p] = r;
    }
}

// tnode[t] = owning node of tile t; also fills ONLY the real pad slots
// (tail of each node's padded range) with the poison record.
__global__ void tfill_kernel(const int* __restrict__ pstart, const int* __restrict__ cnt,
                             int* __restrict__ tnode, int2* __restrict__ pes) {
    int n = blockIdx.x * blockDim.x + threadIdx.x;
    if (n >= N_NODES) return;
    int p0 = pstart[n], p1 = pstart[n + 1];
    for (int t = p0 >> 4; t < (p1 >> 4); ++t) tnode[t] = n;
    int2 pad; pad.x = -1; pad.y = N_NODES;
    for (int p = p0 + cnt[n]; p < p1; ++p) pes[p] = pad;
}

// ---------------------------------------------------------------------------
// xprep: permuted bf16 node features; stored[n][4c+t] = bf16(x[n][16t+c]).
// Row N_NODES (xb and hb) = -1e30 poison.
// ---------------------------------------------------------------------------
__global__ void xprep_kernel(const float* __restrict__ x, short* __restrict__ xb,
                             short* __restrict__ hb) {
    int t = blockIdx.x * blockDim.x + threadIdx.x;
    if (t >= (N_NODES + 1) * 64) return;
    int n = t >> 6, k = t & 63;
    if (n == N_NODES) {
        short pz = f2bf(-1e30f);
        xb[t] = pz;
        hb[t] = pz;
        return;
    }
    int dim = 16 * (k & 3) + (k >> 2);
    xb[(size_t)n * 64 + k] = f2bf(x[(size_t)n * 64 + dim]);
}

// ---------------------------------------------------------------------------
// Edge kernel: flat padded-tile list, direct f32 ea gather via pes.x,
// 3-deep software pipeline (idx 3 ahead, ea 2 ahead, xb 1 ahead),
// wave-uniform run-carry flush; plain store for wave-owned nodes,
// atomicAdd only at wave-boundary nodes.
// ---------------------------------------------------------------------------
__global__ void __launch_bounds__(256) edge_kernel(
    const short* __restrict__ xb,     // [N+1,64] bf16 permuted (+poison row)
    const float* __restrict__ ea,     // [E,32] f32 original order
    const float* __restrict__ We,     // [32,64]
    const float* __restrict__ be,     // [64]
    const int2*  __restrict__ pes,    // [EPAD] {edge id (-1 pad), src (N pad)}
    const int*   __restrict__ tnode,  // [ntiles] owning node per tile
    const int*   __restrict__ pstart, // [N+1] padded offsets; [N]=EPAD
    float* __restrict__ aggr)         // [N,64] pre-zeroed
{
    const int lane = threadIdx.x & 63;
    const int q = lane >> 4;       // 0..3
    const int c = lane & 15;       // 0..15
    const int wave  = (blockIdx.x * blockDim.x + threadIdx.x) >> 6;
    const int nwav  = (gridDim.x * blockDim.x) >> 6;

    const int ntiles = pstart[N_NODES] >> 4;
    const int t0 = (int)(((long long)ntiles * wave) / nwav);
    const int t1 = (int)(((long long)ntiles * (wave + 1)) / nwav);
    if (t0 >= t1) return;

    // B fragments for We (32x64 -> 4 col-tiles of 16). Same k-map as A.
    bf16x8 bfrag[4];
    #pragma unroll
    for (int t = 0; t < 4; ++t) {
        #pragma unroll
        for (int e = 0; e < 8; ++e) {
            int k = 4 * q + (e & 3) + 16 * (e >> 2);
            bfrag[t][e] = f2bf(We[k * 64 + 16 * t + c]);
        }
    }
    // bias folded into MFMA C operand
    f32x4 cb[4];
    #pragma unroll
    for (int t = 0; t < 4; ++t) {
        float bv = be[16 * t + c];
        cb[t][0] = bv; cb[t][1] = bv; cb[t][2] = bv; cb[t][3] = bv;
    }

    auto loadIdx = [&](int tt, int& tn, int& pm, int4& s4) {
        const int2* p = pes + (size_t)tt * 16;
        int4 a = *reinterpret_cast<const int4*>(p + 4 * q);
        int4 b = *reinterpret_cast<const int4*>(p + 4 * q + 2);
        tn = tnode[tt];
        pm = p[c].x;
        s4.x = a.y; s4.y = a.w; s4.z = b.y; s4.w = b.w;
    };
    auto loadEa = [&](int pm, float4& e0, float4& e1) {
        int ep = pm < 0 ? 0 : pm;
        const float* ar = ea + (size_t)ep * EDIM + 4 * q;
        e0 = *reinterpret_cast<const float4*>(ar);
        e1 = *reinterpret_cast<const float4*>(ar + 16);
    };
    auto loadXv = [&](const int4& s4, short4v& x0, short4v& x1,
                      short4v& x2, short4v& x3) {
        x0 = *reinterpret_cast<const short4v*>(xb + (size_t)s4.x * 64 + 4 * c);
        x1 = *reinterpret_cast<const short4v*>(xb + (size_t)s4.y * 64 + 4 * c);
        x2 = *reinterpret_cast<const short4v*>(xb + (size_t)s4.z * 64 + 4 * c);
        x3 = *reinterpret_cast<const short4v*>(xb + (size_t)s4.w * 64 + 4 * c);
    };

    int prev_n = -1;
    float acc0 = 0.f, acc1 = 0.f, acc2 = 0.f, acc3 = 0.f;

    auto flush = [&](int n) {
        float r0 = acc0 + __shfl_xor(acc0, 16, 64);
        float r1 = acc1 + __shfl_xor(acc1, 16, 64);
        float r2 = acc2 + __shfl_xor(acc2, 16, 64);
        float r3 = acc3 + __shfl_xor(acc3, 16, 64);
        r0 += __shfl_xor(r0, 32, 64);
        r1 += __shfl_xor(r1, 32, 64);
        r2 += __shfl_xor(r2, 32, 64);
        r3 += __shfl_xor(r3, 32, 64);
        float v = (q == 0) ? r0 : (q == 1) ? r1 : (q == 2) ? r2 : r3;
        float* dp = aggr + (size_t)n * 64 + lane;
        int a0 = pstart[n] >> 4, a1 = pstart[n + 1] >> 4;
        if (a0 >= t0 && a1 <= t1) *dp = v;   // wave owns whole node: single writer
        else atomicAdd(dp, v);
    };

    // ---- 3-deep pipeline prologue ----
    int tn0, pm0, tn1, pm1, tn2, pm2;
    int4 s40, s41, s42;
    loadIdx(t0, tn0, pm0, s40);
    loadIdx(t0 + 1 < t1 ? t0 + 1 : t1 - 1, tn1, pm1, s41);
    loadIdx(t0 + 2 < t1 ? t0 + 2 : t1 - 1, tn2, pm2, s42);

    float4 ea00, ea01, ea10, ea11;
    short4v xv0, xv1, xv2, xv3;
    loadEa(pm0, ea00, ea01);
    loadEa(pm1, ea10, ea11);
    loadXv(s40, xv0, xv1, xv2, xv3);

    for (int tile = t0; tile < t1; ++tile) {
        // issue ea for tile+2 (2-iteration latency cover on the random gather)
        float4 ea20, ea21;
        loadEa(pm2, ea20, ea21);
        // issue xb for tile+1 (L2-resident, 1 iteration is enough)
        short4v y0, y1, y2, y3;
        loadXv(s41, y0, y1, y2, y3);
        // issue idx for tile+3
        int tn3, pm3; int4 s43;
        loadIdx(tile + 3 < t1 ? tile + 3 : t1 - 1, tn3, pm3, s43);

        // flush when owning node changes (wave-uniform branch, rare)
        if (tn0 != prev_n) {
            if (prev_n >= 0) flush(prev_n);
            prev_n = tn0;
            acc0 = acc1 = acc2 = acc3 = 0.f;
        }

        // convert tile ea rows to bf16 A-fragment (v_cvt_pk_bf16_f32 ×4)
        int4 af;
        af.x = cvt_pk_bf16(ea00.x, ea00.y);
        af.y = cvt_pk_bf16(ea00.z, ea00.w);
        af.z = cvt_pk_bf16(ea01.x, ea01.y);
        af.w = cvt_pk_bf16(ea01.z, ea01.w);
        bf16x8 afrag = __builtin_bit_cast(bf16x8, af);

        f32x4 d[4];
        #pragma unroll
        for (int t = 0; t < 4; ++t)
            d[t] = __builtin_amdgcn_mfma_f32_16x16x32_bf16(afrag, bfrag[t], cb[t], 0, 0, 0);

        // accumulate relu(d + x[src]); pads (-1e30 poison) contribute 0
        const short4v xv[4] = {xv0, xv1, xv2, xv3};
        #pragma unroll
        for (int r = 0; r < 4; ++r) {
            acc0 += fmaxf(d[0][r] + bf2f(xv[r][0]), 0.f);
            acc1 += fmaxf(d[1][r] + bf2f(xv[r][1]), 0.f);
            acc2 += fmaxf(d[2][r] + bf2f(xv[r][2]), 0.f);
            acc3 += fmaxf(d[3][r] + bf2f(xv[r][3]), 0.f);
        }

        // shift pipeline
        tn0 = tn1; pm0 = pm1; s40 = s41;
        tn1 = tn2; pm1 = pm2; s41 = s42;
        tn2 = tn3; pm2 = pm3; s42 = s43;
        ea00 = ea10; ea01 = ea11;
        ea10 = ea20; ea11 = ea21;
        xv0 = y0; xv1 = y1; xv2 = y2; xv3 = y3;
    }
    if (prev_n >= 0) flush(prev_n);
}

// ---------------------------------------------------------------------------
// Node kernel (MFMA): wave per 16-node tile.
// h = relu((x + aggr) @ Wab + bab); writes f32 h and permuted bf16 hb.
// ---------------------------------------------------------------------------
__global__ void __launch_bounds__(256) node_kernel(
    const float* __restrict__ x,
    const float* __restrict__ aggr,
    const float* __restrict__ Wab,    // [64,64] f32
    const float* __restrict__ bab,    // [64]
    float* __restrict__ out,          // [N,64]
    short* __restrict__ hb)           // [N(+1),64] bf16 permuted
{
    const int lane = threadIdx.x & 63;
    const int q = lane >> 4;
    const int c = lane & 15;
    const int wave = (blockIdx.x * blockDim.x + threadIdx.x) >> 6;
    const int nwav = (gridDim.x * blockDim.x) >> 6;

    bf16x8 bfrag[2][4];
    #pragma unroll
    for (int kk = 0; kk < 2; ++kk) {
        #pragma unroll
        for (int t = 0; t < 4; ++t) {
            #pragma unroll
            for (int e = 0; e < 8; ++e) {
                int k = 32 * kk + 4 * q + (e & 3) + 16 * (e >> 2);
                bfrag[kk][t][e] = f2bf(Wab[k * 64 + 16 * t + c]);
            }
        }
    }
    f32x4 cb[4];
    #pragma unroll
    for (int t = 0; t < 4; ++t) {
        float bv = bab[16 * t + c];
        cb[t][0] = bv; cb[t][1] = bv; cb[t][2] = bv; cb[t][3] = bv;
    }

    const int ntile = N_NODES / 16;   // 3125 exact
    for (int nt = wave; nt < ntile; nt += nwav) {
        const int n0 = nt * 16;
        const float* xr = x    + (size_t)(n0 + c) * 64;
        const float* ar = aggr + (size_t)(n0 + c) * 64;
        float4 v[4];
        #pragma unroll
        for (int j = 0; j < 4; ++j) {
            int off = (j >> 1) * 32 + (j & 1) * 16 + 4 * q;
            float4 a = *reinterpret_cast<const float4*>(xr + off);
            float4 b = *reinterpret_cast<const float4*>(ar + off);
            v[j].x = a.x + b.x; v[j].y = a.y + b.y;
            v[j].z = a.z + b.z; v[j].w = a.w + b.w;
        }
        f32x4 d[4];
        #pragma unroll
        for (int kk = 0; kk < 2; ++kk) {
            int4 ai;
            ai.x = cvt_pk_bf16(v[2 * kk].x, v[2 * kk].y);
            ai.y = cvt_pk_bf16(v[2 * kk].z, v[2 * kk].w);
            ai.z = cvt_pk_bf16(v[2 * kk + 1].x, v[2 * kk + 1].y);
            ai.w = cvt_pk_bf16(v[2 * kk + 1].z, v[2 * kk + 1].w);
            bf16x8 afrag = __builtin_bit_cast(bf16x8, ai);
            #pragma unroll
            for (int t = 0; t < 4; ++t)
                d[t] = __builtin_amdgcn_mfma_f32_16x16x32_bf16(
                    afrag, bfrag[kk][t], kk == 0 ? cb[t] : d[t], 0, 0, 0);
        }
        #pragma unroll
        for (int r = 0; r < 4; ++r) {
            float h0 = fmaxf(d[0][r], 0.f);
            float h1v = fmaxf(d[1][r], 0.f);
            float h2v = fmaxf(d[2][r], 0.f);
            float h3 = fmaxf(d[3][r], 0.f);
            float* orow = out + (size_t)(n0 + 4 * q + r) * 64;
            orow[c]      = h0;
            orow[16 + c] = h1v;
            orow[32 + c] = h2v;
            orow[48 + c] = h3;
            int2 pk;
            pk.x = cvt_pk_bf16(h0, h1v);
            pk.y = cvt_pk_bf16(h2v, h3);
            *reinterpret_cast<int2*>(hb + (size_t)(n0 + 4 * q + r) * 64 + 4 * c) = pk;
        }
    }
}

__global__ void prep_kernel(
    const float* __restrict__ Wa1, const float* __restrict__ ba1,
    const float* __restrict__ Wb1, const float* __restrict__ bb1,
    const float* __restrict__ Wa2, const float* __restrict__ ba2,
    const float* __restrict__ Wb2, const float* __restrict__ bb2,
    float* __restrict__ Wab1, float* __restrict__ bab1,
    float* __restrict__ Wab2, float* __restrict__ bab2)
{
    const int t = threadIdx.x;
    for (int idx = t; idx < 64 * 64; idx += 256) {
        int i = idx >> 6, j = idx & 63;
        float s1 = 0.f, s2 = 0.f;
        for (int m = 0; m < 64; ++m) {
            s1 += Wa1[i * 64 + m] * Wb1[m * 64 + j];
            s2 += Wa2[i * 64 + m] * Wb2[m * 64 + j];
        }
        Wab1[idx] = s1; Wab2[idx] = s2;
    }
    for (int j = t; j < 64; j += 256) {
        float s1 = bb1[j], s2 = bb2[j];
        for (int m = 0; m < 64; ++m) {
            s1 += ba1[m] * Wb1[m * 64 + j];
            s2 += ba2[m] * Wb2[m * 64 + j];
        }
        bab1[j] = s1; bab2[j] = s2;
    }
}

__global__ void __launch_bounds__(256) pool_kernel(
    const float* __restrict__ h,
    const int*   __restrict__ batch,
    float* __restrict__ psum,
    float* __restrict__ pcnt)
{
    const int lane = threadIdx.x & 63;
    const int wave = (blockIdx.x * blockDim.x + threadIdx.x) >> 6;
    const int n0 = wave * 64;
    if (n0 >= N_NODES) return;
    const int nend = min(n0 + 64, N_NODES);

    int cur = batch[n0];
    float acc = 0.f;
    int cnt = 0;
    for (int n = n0; n < nend; ++n) {
        int b = batch[n];
        if (b != cur) {
            atomicAdd(&psum[(size_t)cur * 64 + lane], acc);
            if (lane == 0) atomicAdd(&pcnt[cur], (float)cnt);
            cur = b; acc = 0.f; cnt = 0;
        }
        acc += h[(size_t)n * 64 + lane];
        cnt++;
    }
    atomicAdd(&psum[(size_t)cur * 64 + lane], acc);
    if (lane == 0) atomicAdd(&pcnt[cur], (float)cnt);
}

__global__ void final_kernel(
    const float* __restrict__ psum, const float* __restrict__ pcnt,
    const float* __restrict__ Wf, const float* __restrict__ bfv,
    float* __restrict__ out)
{
    __shared__ float pooled[NUM_GRAPHS * 64];
    __shared__ float logits[NUM_GRAPHS * NUM_CLASSES];
    const int t = threadIdx.x;
    for (int idx = t; idx < NUM_GRAPHS * 64; idx += 256) {
        int g = idx >> 6;
        float cc = pcnt[g];
        cc = cc < 1.f ? 1.f : cc;
        pooled[idx] = psum[idx] / cc;
    }
    __syncthreads();
    for (int idx = t; idx < NUM_GRAPHS * NUM_CLASSES; idx += 256) {
        int g = idx / NUM_CLASSES, cc = idx % NUM_CLASSES;
        float acc = bfv[cc];
        for (int k = 0; k < 64; ++k)
            acc += pooled[g * 64 + k] * Wf[k * NUM_CLASSES + cc];
        logits[idx] = acc;
    }
    __syncthreads();
    if (t < NUM_GRAPHS) {
        float mx = -1e30f;
        for (int cc = 0; cc < NUM_CLASSES; ++cc)
            mx = fmaxf(mx, logits[t * NUM_CLASSES + cc]);
        float s = 0.f;
        float ex[NUM_CLASSES];
        for (int cc = 0; cc < NUM_CLASSES; ++cc) {
            ex[cc] = expf(logits[t * NUM_CLASSES + cc] - mx);
            s += ex[cc];
        }
        for (int cc = 0; cc < NUM_CLASSES; ++cc)
            out[t * NUM_CLASSES + cc] = ex[cc] / s;
    }
}

extern "C" void kernel_launch(void* const* d_in, const int* in_sizes, int n_in,
                              void* d_out, int out_size, void* d_ws, size_t ws_size,
                              hipStream_t stream) {
    const float* x   = (const float*)d_in[0];
    const float* ea  = (const float*)d_in[1];
    const float* We1 = (const float*)d_in[2];
    const float* be1 = (const float*)d_in[3];
    const float* W1a = (const float*)d_in[4];
    const float* b1a = (const float*)d_in[5];
    const float* W1b = (const float*)d_in[6];
    const float* b1b = (const float*)d_in[7];
    const float* We2 = (const float*)d_in[8];
    const float* be2 = (const float*)d_in[9];
    const float* W2a = (const float*)d_in[10];
    const float* b2a = (const float*)d_in[11];
    const float* W2b = (const float*)d_in[12];
    const float* b2b = (const float*)d_in[13];
    const float* Wf  = (const float*)d_in[14];
    const float* bfv = (const float*)d_in[15];
    const int* ei    = (const int*)d_in[16];
    const int* batch = (const int*)d_in[17];
    const int* src = ei;
    const int* dst = ei + N_EDGES;

    float* ws   = (float*)d_ws;
    float* aggr = ws;                      // 3.2M f
    float* h1   = ws + 3200000;            // 3.2M f
    float* h2   = ws + 6400000;            // 3.2M f
    float* Wab1 = ws + 9600000;            // 4096
    float* bab1 = Wab1 + 4096;             // 64
    float* Wab2 = bab1 + 64;               // 4096
    float* bab2 = Wab2 + 4096;             // 64
    float* psum = bab2 + 64;               // 8192
    float* pcnt = psum + 8192;             // 128
    int* cnt    = (int*)(pcnt + 128);      // NBIN_PAD
    int* pstart = cnt + NBIN_PAD;          // NBIN_PAD
    int* cursor = pstart + NBIN_PAD;       // NBIN_PAD
    int* partial= cursor + NBIN_PAD;       // 256
    int2* pes   = (int2*)(partial + 256);  // EPAD_MAX int2 (== 2*EPAD_MAX ints)
    int* tnode  = (int*)(pes + EPAD_MAX);  // EPAD_MAX/16
    short* xb   = (short*)(tnode + EPAD_MAX / 16);  // (N+1)*64 shorts
    short* hb1  = xb + (size_t)(N_NODES + 1) * 64;  // (N+1)*64 shorts
    short* hb2  = hb1 + (size_t)(N_NODES + 1) * 64; // (N+1)*64 shorts (dummy)

    float* out = (float*)d_out;

    // ---- padded-CSR build (no full pad pre-fill: tfill fills only real pads) ----
    hipMemsetAsync(cnt, 0, NBIN_PAD * sizeof(int), stream);
    hist_kernel<<<1024, 256, 0, stream>>>(dst, cnt);
    scan_part<<<NSCAN_BLK, 256, 0, stream>>>(cnt, pstart, partial);
    scan_mid<<<1, 256, 0, stream>>>(partial);
    scan_add<<<NSCAN_BLK, 256, 0, stream>>>(pstart, partial, cursor);
    scatter_kernel<<<1024, 256, 0, stream>>>(src, dst, cursor, pes);
    tfill_kernel<<<(N_NODES + 255) / 256, 256, 0, stream>>>(pstart, cnt, tnode, pes);
    xprep_kernel<<<((N_NODES + 1) * 64 + 255) / 256, 256, 0, stream>>>(x, xb, hb1);

    hipMemsetAsync(psum, 0, (8192 + 128) * sizeof(float), stream);
    prep_kernel<<<1, 256, 0, stream>>>(W1a, b1a, W1b, b1b, W2a, b2a, W2b, b2b,
                                       Wab1, bab1, Wab2, bab2);

    hipMemsetAsync(aggr, 0, (size_t)N_NODES * DIM * sizeof(float), stream);
    edge_kernel<<<2048, 256, 0, stream>>>(xb, ea, We1, be1, pes, tnode, pstart, aggr);
    node_kernel<<<512, 256, 0, stream>>>(x, aggr, Wab1, bab1, h1, hb1);

    hipMemsetAsync(aggr, 0, (size_t)N_NODES * DIM * sizeof(float), stream);
    edge_kernel<<<2048, 256, 0, stream>>>(hb1, ea, We2, be2, pes, tnode, pstart, aggr);
    node_kernel<<<512, 256, 0, stream>>>(h1, aggr, Wab2, bab2, h2, hb2);

    pool_kernel<<<196, 256, 0, stream>>>(h2, batch, psum, pcnt);
    final_kernel<<<1, 256, 0, stream>>>(psum, pcnt, Wf, bfv, out);
}

// Round 2
// 344.880 us; speedup vs baseline: 1.4873x; 1.4873x over previous
//
#include <hip/hip_runtime.h>

#define N_NODES 50000
#define N_EDGES 1600000
#define DIM 64
#define EDIM 32
#define NUM_GRAPHS 128
#define NUM_CLASSES 10
#define NBIN_PAD 50176            // 196*256 >= N_NODES+1
#define NSCAN_BLK 196
#define EPAD_MAX 2200000          // >= sum(ceil(deg/16)*16)
#define NBUCK 196                 // coarse buckets: dst >> 8
#define BCAP 12288                // per-bucket capacity (mean 8192, +45 sigma)
#define ACH 4096                  // edges per binA block

typedef __attribute__((ext_vector_type(8))) short bf16x8;
typedef __attribute__((ext_vector_type(4))) short short4v;
typedef __attribute__((ext_vector_type(4))) float f32x4;

static __device__ __forceinline__ short f2bf(float f) {
    unsigned u = __builtin_bit_cast(unsigned, f);
    u += 0x7fff + ((u >> 16) & 1);   // round-to-nearest-even
    return (short)(u >> 16);
}
static __device__ __forceinline__ float bf2f(short s) {
    unsigned u = ((unsigned)(unsigned short)s) << 16;
    return __builtin_bit_cast(float, u);
}
// pack 2 f32 -> 2 bf16 in one v_cvt_pk_bf16_f32 (no builtin on gfx950)
static __device__ __forceinline__ int cvt_pk_bf16(float lo, float hi) {
    int r;
    asm("v_cvt_pk_bf16_f32 %0, %1, %2" : "=v"(r) : "v"(lo), "v"(hi));
    return r;
}

// ---------------------------------------------------------------------------
// binA: coarse-bucket edges by dst>>8 with LDS staging. No per-edge global
// atomics: one atomicAdd per (block,bucket) reserves a contiguous run, and
// the flush writes ~21-record coalesced bursts.
// record = {edge id, (dst<<16) | src}
// ---------------------------------------------------------------------------
__global__ void __launch_bounds__(256) binA_kernel(
    const int* __restrict__ src, const int* __restrict__ dst,
    int* __restrict__ bcur, int2* __restrict__ bbuf)
{
    __shared__ int hist[256];
    __shared__ int scanb[256];
    __shared__ int bexcl[256];
    __shared__ int cursA[256];
    __shared__ int gbase[256];
    __shared__ int2 st[ACH];

    const int t = threadIdx.x;
    const int e0 = blockIdx.x * ACH;
    const int nv = min(ACH, N_EDGES - e0);

    hist[t] = 0;
    __syncthreads();

    int w1[ACH / 256];
    #pragma unroll
    for (int i = 0; i < ACH / 256; ++i) {
        int idx = t + 256 * i;
        if (idx < nv) {
            int e = e0 + idx;
            int d = dst[e], s = src[e];
            w1[i] = (s & 0xFFFF) | (d << 16);
            atomicAdd(&hist[(unsigned)w1[i] >> 24], 1);
        } else {
            w1[i] = -1;
        }
    }
    __syncthreads();

    // exclusive scan of hist -> bexcl; reserve global runs
    int v = hist[t];
    scanb[t] = v;
    __syncthreads();
    #pragma unroll
    for (int off = 1; off < 256; off <<= 1) {
        int add = (t >= off) ? scanb[t - off] : 0;
        __syncthreads();
        scanb[t] += add;
        __syncthreads();
    }
    int excl = scanb[t] - v;
    bexcl[t] = excl;
    cursA[t] = excl;
    if (v > 0) gbase[t] = atomicAdd(&bcur[t], v);
    __syncthreads();

    // place into LDS staging, sorted by bucket
    #pragma unroll
    for (int i = 0; i < ACH / 256; ++i) {
        int idx = t + 256 * i;
        if (idx < nv) {
            int b = (unsigned)w1[i] >> 24;
            int r = atomicAdd(&cursA[b], 1);
            int2 rec; rec.x = e0 + idx; rec.y = w1[i];
            st[r] = rec;
        }
    }
    __syncthreads();

    // flush: consecutive k within a bucket-run -> consecutive global addrs
    for (int k = t; k < nv; k += 256) {
        int2 rec = st[k];
        int b = (unsigned)rec.y >> 24;
        int pos = gbase[b] + (k - bexcl[b]);
        if (pos < BCAP) bbuf[(size_t)b * BCAP + pos] = rec;
    }
}

// ---------------------------------------------------------------------------
// binB1: per-bucket node histogram (256 nodes) entirely in LDS.
// Replaces the global-atomic hist_kernel. Writes ALL cnt entries (no memset).
// ---------------------------------------------------------------------------
__global__ void __launch_bounds__(1024) binB1_kernel(
    const int* __restrict__ bcur, const int2* __restrict__ bbuf,
    int* __restrict__ cnt)
{
    __shared__ int nodecnt[256];
    const int b = blockIdx.x, t = threadIdx.x;
    if (t < 256) nodecnt[t] = 0;
    __syncthreads();
    const int nb = min(bcur[b], BCAP);
    for (int k = t; k < nb; k += 1024) {
        int2 rec = bbuf[(size_t)b * BCAP + k];
        int dlow = ((unsigned)rec.y >> 16) & 0xFF;
        atomicAdd(&nodecnt[dlow], 1);
    }
    __syncthreads();
    if (t < 256) cnt[b * 256 + t] = nodecnt[t];
}

// Exclusive scan of PADDED degrees (ceil(deg/16)*16) -> pstart.
__global__ void scan_part(const int* __restrict__ cnt, int* __restrict__ pstart,
                          int* __restrict__ partial) {
    __shared__ int sh[256];
    const int b = blockIdx.x, t = threadIdx.x;
    const int i = b * 256 + t;
    int v = ((cnt[i] + 15) >> 4) << 4;
    sh[t] = v;
    __syncthreads();
    #pragma unroll
    for (int off = 1; off < 256; off <<= 1) {
        int add = (t >= off) ? sh[t - off] : 0;
        __syncthreads();
        sh[t] += add;
        __syncthreads();
    }
    pstart[i] = sh[t] - v;
    if (t == 255) partial[b] = sh[t];
}

__global__ void scan_mid(int* __restrict__ partial) {
    __shared__ int sh[256];
    const int t = threadIdx.x;
    int v = (t < NSCAN_BLK) ? partial[t] : 0;
    sh[t] = v;
    __syncthreads();
    #pragma unroll
    for (int off = 1; off < 256; off <<= 1) {
        int add = (t >= off) ? sh[t - off] : 0;
        __syncthreads();
        sh[t] += add;
        __syncthreads();
    }
    if (t < NSCAN_BLK) partial[t] = sh[t] - v;
}

__global__ void scan_add(int* __restrict__ pstart, const int* __restrict__ partial) {
    const int b = blockIdx.x, t = threadIdx.x;
    const int i = b * 256 + t;
    pstart[i] += partial[b];
}

// ---------------------------------------------------------------------------
// binB2: final placement into padded CSR. One block per bucket, so all pes
// writes for a bucket's ~90KB window come from a single CU -> L2-local.
// LDS cursors (no global atomics). Pads + tnode fused.
// ---------------------------------------------------------------------------
__global__ void __launch_bounds__(1024) binB2_kernel(
    const int* __restrict__ bcur, const int2* __restrict__ bbuf,
    const int* __restrict__ pstart, const int* __restrict__ cnt,
    int2* __restrict__ pes, int* __restrict__ tnode)
{
    __shared__ int cur[256];
    const int b = blockIdx.x, t = threadIdx.x;
    if (t < 256) cur[t] = pstart[b * 256 + t];
    __syncthreads();
    const int nb = min(bcur[b], BCAP);
    for (int k = t; k < nb; k += 1024) {
        int2 rec = bbuf[(size_t)b * BCAP + k];
        unsigned y = (unsigned)rec.y;
        int dlow = (y >> 16) & 0xFF;
        int p = atomicAdd(&cur[dlow], 1);
        int2 o; o.x = rec.x; o.y = (int)(y & 0xFFFF);
        pes[p] = o;
    }
    __syncthreads();
    if (t < 256) {
        int n = b * 256 + t;
        if (n < N_NODES) {
            int p0 = pstart[n], deg = cnt[n];
            int pe = p0 + (((deg + 15) >> 4) << 4);
            int2 pad; pad.x = -1; pad.y = N_NODES;
            for (int p = p0 + deg; p < pe; ++p) pes[p] = pad;
            for (int tt = p0 >> 4; tt < (pe >> 4); ++tt) tnode[tt] = n;
        }
    }
}

// ---------------------------------------------------------------------------
// xprep: permuted bf16 node features; stored[n][4c+t] = bf16(x[n][16t+c]).
// Row N_NODES (xb and hb) = -1e30 poison.
// ---------------------------------------------------------------------------
__global__ void xprep_kernel(const float* __restrict__ x, short* __restrict__ xb,
                             short* __restrict__ hb) {
    int t = blockIdx.x * blockDim.x + threadIdx.x;
    if (t >= (N_NODES + 1) * 64) return;
    int n = t >> 6, k = t & 63;
    if (n == N_NODES) {
        short pz = f2bf(-1e30f);
        xb[t] = pz;
        hb[t] = pz;
        return;
    }
    int dim = 16 * (k & 3) + (k >> 2);
    xb[(size_t)n * 64 + k] = f2bf(x[(size_t)n * 64 + dim]);
}

// ---------------------------------------------------------------------------
// Edge kernel: flat padded-tile list, direct f32 ea gather via pes.x,
// 3-deep software pipeline (idx 3 ahead, ea 2 ahead, xb 1 ahead),
// wave-uniform run-carry flush; plain store for wave-owned nodes,
// atomicAdd only at wave-boundary nodes.
// ---------------------------------------------------------------------------
__global__ void __launch_bounds__(256) edge_kernel(
    const short* __restrict__ xb,     // [N+1,64] bf16 permuted (+poison row)
    const float* __restrict__ ea,     // [E,32] f32 original order
    const float* __restrict__ We,     // [32,64]
    const float* __restrict__ be,     // [64]
    const int2*  __restrict__ pes,    // [EPAD] {edge id (-1 pad), src (N pad)}
    const int*   __restrict__ tnode,  // [ntiles] owning node per tile
    const int*   __restrict__ pstart, // [N+1] padded offsets; [N]=EPAD
    float* __restrict__ aggr)         // [N,64] pre-zeroed
{
    const int lane = threadIdx.x & 63;
    const int q = lane >> 4;       // 0..3
    const int c = lane & 15;       // 0..15
    const int wave  = (blockIdx.x * blockDim.x + threadIdx.x) >> 6;
    const int nwav  = (gridDim.x * blockDim.x) >> 6;

    const int ntiles = pstart[N_NODES] >> 4;
    const int t0 = (int)(((long long)ntiles * wave) / nwav);
    const int t1 = (int)(((long long)ntiles * (wave + 1)) / nwav);
    if (t0 >= t1) return;

    // B fragments for We (32x64 -> 4 col-tiles of 16). Same k-map as A.
    bf16x8 bfrag[4];
    #pragma unroll
    for (int t = 0; t < 4; ++t) {
        #pragma unroll
        for (int e = 0; e < 8; ++e) {
            int k = 4 * q + (e & 3) + 16 * (e >> 2);
            bfrag[t][e] = f2bf(We[k * 64 + 16 * t + c]);
        }
    }
    // bias folded into MFMA C operand
    f32x4 cb[4];
    #pragma unroll
    for (int t = 0; t < 4; ++t) {
        float bv = be[16 * t + c];
        cb[t][0] = bv; cb[t][1] = bv; cb[t][2] = bv; cb[t][3] = bv;
    }

    auto loadIdx = [&](int tt, int& tn, int& pm, int4& s4) {
        const int2* p = pes + (size_t)tt * 16;
        int4 a = *reinterpret_cast<const int4*>(p + 4 * q);
        int4 b = *reinterpret_cast<const int4*>(p + 4 * q + 2);
        tn = tnode[tt];
        pm = p[c].x;
        s4.x = a.y; s4.y = a.w; s4.z = b.y; s4.w = b.w;
    };
    auto loadEa = [&](int pm, float4& e0, float4& e1) {
        int ep = pm < 0 ? 0 : pm;
        const float* ar = ea + (size_t)ep * EDIM + 4 * q;
        e0 = *reinterpret_cast<const float4*>(ar);
        e1 = *reinterpret_cast<const float4*>(ar + 16);
    };
    auto loadXv = [&](const int4& s4, short4v& x0, short4v& x1,
                      short4v& x2, short4v& x3) {
        x0 = *reinterpret_cast<const short4v*>(xb + (size_t)s4.x * 64 + 4 * c);
        x1 = *reinterpret_cast<const short4v*>(xb + (size_t)s4.y * 64 + 4 * c);
        x2 = *reinterpret_cast<const short4v*>(xb + (size_t)s4.z * 64 + 4 * c);
        x3 = *reinterpret_cast<const short4v*>(xb + (size_t)s4.w * 64 + 4 * c);
    };

    int prev_n = -1;
    float acc0 = 0.f, acc1 = 0.f, acc2 = 0.f, acc3 = 0.f;

    auto flush = [&](int n) {
        float r0 = acc0 + __shfl_xor(acc0, 16, 64);
        float r1 = acc1 + __shfl_xor(acc1, 16, 64);
        float r2 = acc2 + __shfl_xor(acc2, 16, 64);
        float r3 = acc3 + __shfl_xor(acc3, 16, 64);
        r0 += __shfl_xor(r0, 32, 64);
        r1 += __shfl_xor(r1, 32, 64);
        r2 += __shfl_xor(r2, 32, 64);
        r3 += __shfl_xor(r3, 32, 64);
        float v = (q == 0) ? r0 : (q == 1) ? r1 : (q == 2) ? r2 : r3;
        float* dp = aggr + (size_t)n * 64 + lane;
        int a0 = pstart[n] >> 4, a1 = pstart[n + 1] >> 4;
        if (a0 >= t0 && a1 <= t1) *dp = v;   // wave owns whole node: single writer
        else atomicAdd(dp, v);
    };

    // ---- 3-deep pipeline prologue ----
    int tn0, pm0, tn1, pm1, tn2, pm2;
    int4 s40, s41, s42;
    loadIdx(t0, tn0, pm0, s40);
    loadIdx(t0 + 1 < t1 ? t0 + 1 : t1 - 1, tn1, pm1, s41);
    loadIdx(t0 + 2 < t1 ? t0 + 2 : t1 - 1, tn2, pm2, s42);

    float4 ea00, ea01, ea10, ea11;
    short4v xv0, xv1, xv2, xv3;
    loadEa(pm0, ea00, ea01);
    loadEa(pm1, ea10, ea11);
    loadXv(s40, xv0, xv1, xv2, xv3);

    for (int tile = t0; tile < t1; ++tile) {
        // issue ea for tile+2 (2-iteration latency cover on the random gather)
        float4 ea20, ea21;
        loadEa(pm2, ea20, ea21);
        // issue xb for tile+1 (L2-resident, 1 iteration is enough)
        short4v y0, y1, y2, y3;
        loadXv(s41, y0, y1, y2, y3);
        // issue idx for tile+3
        int tn3, pm3; int4 s43;
        loadIdx(tile + 3 < t1 ? tile + 3 : t1 - 1, tn3, pm3, s43);

        // flush when owning node changes (wave-uniform branch, rare)
        if (tn0 != prev_n) {
            if (prev_n >= 0) flush(prev_n);
            prev_n = tn0;
            acc0 = acc1 = acc2 = acc3 = 0.f;
        }

        // convert tile ea rows to bf16 A-fragment (v_cvt_pk_bf16_f32 ×4)
        int4 af;
        af.x = cvt_pk_bf16(ea00.x, ea00.y);
        af.y = cvt_pk_bf16(ea00.z, ea00.w);
        af.z = cvt_pk_bf16(ea01.x, ea01.y);
        af.w = cvt_pk_bf16(ea01.z, ea01.w);
        bf16x8 afrag = __builtin_bit_cast(bf16x8, af);

        f32x4 d[4];
        #pragma unroll
        for (int t = 0; t < 4; ++t)
            d[t] = __builtin_amdgcn_mfma_f32_16x16x32_bf16(afrag, bfrag[t], cb[t], 0, 0, 0);

        // accumulate relu(d + x[src]); pads (-1e30 poison) contribute 0
        const short4v xv[4] = {xv0, xv1, xv2, xv3};
        #pragma unroll
        for (int r = 0; r < 4; ++r) {
            acc0 += fmaxf(d[0][r] + bf2f(xv[r][0]), 0.f);
            acc1 += fmaxf(d[1][r] + bf2f(xv[r][1]), 0.f);
            acc2 += fmaxf(d[2][r] + bf2f(xv[r][2]), 0.f);
            acc3 += fmaxf(d[3][r] + bf2f(xv[r][3]), 0.f);
        }

        // shift pipeline
        tn0 = tn1; pm0 = pm1; s40 = s41;
        tn1 = tn2; pm1 = pm2; s41 = s42;
        tn2 = tn3; pm2 = pm3; s42 = s43;
        ea00 = ea10; ea01 = ea11;
        ea10 = ea20; ea11 = ea21;
        xv0 = y0; xv1 = y1; xv2 = y2; xv3 = y3;
    }
    if (prev_n >= 0) flush(prev_n);
}

// ---------------------------------------------------------------------------
// Node kernel (MFMA): wave per 16-node tile.
// h = relu((x + aggr) @ Wab + bab); writes f32 h and permuted bf16 hb.
// ---------------------------------------------------------------------------
__global__ void __launch_bounds__(256) node_kernel(
    const float* __restrict__ x,
    const float* __restrict__ aggr,
    const float* __restrict__ Wab,    // [64,64] f32
    const float* __restrict__ bab,    // [64]
    float* __restrict__ out,          // [N,64]
    short* __restrict__ hb)           // [N(+1),64] bf16 permuted
{
    const int lane = threadIdx.x & 63;
    const int q = lane >> 4;
    const int c = lane & 15;
    const int wave = (blockIdx.x * blockDim.x + threadIdx.x) >> 6;
    const int nwav = (gridDim.x * blockDim.x) >> 6;

    bf16x8 bfrag[2][4];
    #pragma unroll
    for (int kk = 0; kk < 2; ++kk) {
        #pragma unroll
        for (int t = 0; t < 4; ++t) {
            #pragma unroll
            for (int e = 0; e < 8; ++e) {
                int k = 32 * kk + 4 * q + (e & 3) + 16 * (e >> 2);
                bfrag[kk][t][e] = f2bf(Wab[k * 64 + 16 * t + c]);
            }
        }
    }
    f32x4 cb[4];
    #pragma unroll
    for (int t = 0; t < 4; ++t) {
        float bv = bab[16 * t + c];
        cb[t][0] = bv; cb[t][1] = bv; cb[t][2] = bv; cb[t][3] = bv;
    }

    const int ntile = N_NODES / 16;   // 3125 exact
    for (int nt = wave; nt < ntile; nt += nwav) {
        const int n0 = nt * 16;
        const float* xr = x    + (size_t)(n0 + c) * 64;
        const float* ar = aggr + (size_t)(n0 + c) * 64;
        float4 v[4];
        #pragma unroll
        for (int j = 0; j < 4; ++j) {
            int off = (j >> 1) * 32 + (j & 1) * 16 + 4 * q;
            float4 a = *reinterpret_cast<const float4*>(xr + off);
            float4 b = *reinterpret_cast<const float4*>(ar + off);
            v[j].x = a.x + b.x; v[j].y = a.y + b.y;
            v[j].z = a.z + b.z; v[j].w = a.w + b.w;
        }
        f32x4 d[4];
        #pragma unroll
        for (int kk = 0; kk < 2; ++kk) {
            int4 ai;
            ai.x = cvt_pk_bf16(v[2 * kk].x, v[2 * kk].y);
            ai.y = cvt_pk_bf16(v[2 * kk].z, v[2 * kk].w);
            ai.z = cvt_pk_bf16(v[2 * kk + 1].x, v[2 * kk + 1].y);
            ai.w = cvt_pk_bf16(v[2 * kk + 1].z, v[2 * kk + 1].w);
            bf16x8 afrag = __builtin_bit_cast(bf16x8, ai);
            #pragma unroll
            for (int t = 0; t < 4; ++t)
                d[t] = __builtin_amdgcn_mfma_f32_16x16x32_bf16(
                    afrag, bfrag[kk][t], kk == 0 ? cb[t] : d[t], 0, 0, 0);
        }
        #pragma unroll
        for (int r = 0; r < 4; ++r) {
            float h0 = fmaxf(d[0][r], 0.f);
            float h1v = fmaxf(d[1][r], 0.f);
            float h2v = fmaxf(d[2][r], 0.f);
            float h3 = fmaxf(d[3][r], 0.f);
            float* orow = out + (size_t)(n0 + 4 * q + r) * 64;
            orow[c]      = h0;
            orow[16 + c] = h1v;
            orow[32 + c] = h2v;
            orow[48 + c] = h3;
            int2 pk;
            pk.x = cvt_pk_bf16(h0, h1v);
            pk.y = cvt_pk_bf16(h2v, h3);
            *reinterpret_cast<int2*>(hb + (size_t)(n0 + 4 * q + r) * 64 + 4 * c) = pk;
        }
    }
}

__global__ void prep_kernel(
    const float* __restrict__ Wa1, const float* __restrict__ ba1,
    const float* __restrict__ Wb1, const float* __restrict__ bb1,
    const float* __restrict__ Wa2, const float* __restrict__ ba2,
    const float* __restrict__ Wb2, const float* __restrict__ bb2,
    float* __restrict__ Wab1, float* __restrict__ bab1,
    float* __restrict__ Wab2, float* __restrict__ bab2)
{
    const int t = threadIdx.x;
    for (int idx = t; idx < 64 * 64; idx += 256) {
        int i = idx >> 6, j = idx & 63;
        float s1 = 0.f, s2 = 0.f;
        for (int m = 0; m < 64; ++m) {
            s1 += Wa1[i * 64 + m] * Wb1[m * 64 + j];
            s2 += Wa2[i * 64 + m] * Wb2[m * 64 + j];
        }
        Wab1[idx] = s1; Wab2[idx] = s2;
    }
    for (int j = t; j < 64; j += 256) {
        float s1 = bb1[j], s2 = bb2[j];
        for (int m = 0; m < 64; ++m) {
            s1 += ba1[m] * Wb1[m * 64 + j];
            s2 += ba2[m] * Wb2[m * 64 + j];
        }
        bab1[j] = s1; bab2[j] = s2;
    }
}

__global__ void __launch_bounds__(256) pool_kernel(
    const float* __restrict__ h,
    const int*   __restrict__ batch,
    float* __restrict__ psum,
    float* __restrict__ pcnt)
{
    const int lane = threadIdx.x & 63;
    const int wave = (blockIdx.x * blockDim.x + threadIdx.x) >> 6;
    const int n0 = wave * 64;
    if (n0 >= N_NODES) return;
    const int nend = min(n0 + 64, N_NODES);

    int cur = batch[n0];
    float acc = 0.f;
    int cnt = 0;
    for (int n = n0; n < nend; ++n) {
        int b = batch[n];
        if (b != cur) {
            atomicAdd(&psum[(size_t)cur * 64 + lane], acc);
            if (lane == 0) atomicAdd(&pcnt[cur], (float)cnt);
            cur = b; acc = 0.f; cnt = 0;
        }
        acc += h[(size_t)n * 64 + lane];
        cnt++;
    }
    atomicAdd(&psum[(size_t)cur * 64 + lane], acc);
    if (lane == 0) atomicAdd(&pcnt[cur], (float)cnt);
}

__global__ void final_kernel(
    const float* __restrict__ psum, const float* __restrict__ pcnt,
    const float* __restrict__ Wf, const float* __restrict__ bfv,
    float* __restrict__ out)
{
    __shared__ float pooled[NUM_GRAPHS * 64];
    __shared__ float logits[NUM_GRAPHS * NUM_CLASSES];
    const int t = threadIdx.x;
    for (int idx = t; idx < NUM_GRAPHS * 64; idx += 256) {
        int g = idx >> 6;
        float cc = pcnt[g];
        cc = cc < 1.f ? 1.f : cc;
        pooled[idx] = psum[idx] / cc;
    }
    __syncthreads();
    for (int idx = t; idx < NUM_GRAPHS * NUM_CLASSES; idx += 256) {
        int g = idx / NUM_CLASSES, cc = idx % NUM_CLASSES;
        float acc = bfv[cc];
        for (int k = 0; k < 64; ++k)
            acc += pooled[g * 64 + k] * Wf[k * NUM_CLASSES + cc];
        logits[idx] = acc;
    }
    __syncthreads();
    if (t < NUM_GRAPHS) {
        float mx = -1e30f;
        for (int cc = 0; cc < NUM_CLASSES; ++cc)
            mx = fmaxf(mx, logits[t * NUM_CLASSES + cc]);
        float s = 0.f;
        float ex[NUM_CLASSES];
        for (int cc = 0; cc < NUM_CLASSES; ++cc) {
            ex[cc] = expf(logits[t * NUM_CLASSES + cc] - mx);
            s += ex[cc];
        }
        for (int cc = 0; cc < NUM_CLASSES; ++cc)
            out[t * NUM_CLASSES + cc] = ex[cc] / s;
    }
}

extern "C" void kernel_launch(void* const* d_in, const int* in_sizes, int n_in,
                              void* d_out, int out_size, void* d_ws, size_t ws_size,
                              hipStream_t stream) {
    const float* x   = (const float*)d_in[0];
    const float* ea  = (const float*)d_in[1];
    const float* We1 = (const float*)d_in[2];
    const float* be1 = (const float*)d_in[3];
    const float* W1a = (const float*)d_in[4];
    const float* b1a = (const float*)d_in[5];
    const float* W1b = (const float*)d_in[6];
    const float* b1b = (const float*)d_in[7];
    const float* We2 = (const float*)d_in[8];
    const float* be2 = (const float*)d_in[9];
    const float* W2a = (const float*)d_in[10];
    const float* b2a = (const float*)d_in[11];
    const float* W2b = (const float*)d_in[12];
    const float* b2b = (const float*)d_in[13];
    const float* Wf  = (const float*)d_in[14];
    const float* bfv = (const float*)d_in[15];
    const int* ei    = (const int*)d_in[16];
    const int* batch = (const int*)d_in[17];
    const int* src = ei;
    const int* dst = ei + N_EDGES;

    float* ws   = (float*)d_ws;
    float* aggr = ws;                      // 3.2M f
    float* h1   = ws + 3200000;            // 3.2M f
    float* h2   = ws + 6400000;            // 3.2M f
    float* Wab1 = ws + 9600000;            // 4096
    float* bab1 = Wab1 + 4096;             // 64
    float* Wab2 = bab1 + 64;               // 4096
    float* bab2 = Wab2 + 4096;             // 64
    float* psum = bab2 + 64;               // 8192
    float* pcnt = psum + 8192;             // 128
    int* cnt    = (int*)(pcnt + 128);      // NBIN_PAD
    int* pstart = cnt + NBIN_PAD;          // NBIN_PAD
    int* partial= pstart + NBIN_PAD;       // 256
    int* bcur   = partial + 256;           // 256
    int2* bbuf  = (int2*)(bcur + 256);     // NBUCK*BCAP int2 (19.3MB)
    int2* pes   = bbuf + (size_t)NBUCK * BCAP;  // EPAD_MAX int2
    int* tnode  = (int*)(pes + EPAD_MAX);  // EPAD_MAX/16
    short* xb   = (short*)(tnode + EPAD_MAX / 16);  // (N+1)*64 shorts
    short* hb1  = xb + (size_t)(N_NODES + 1) * 64;  // (N+1)*64 shorts
    short* hb2  = hb1 + (size_t)(N_NODES + 1) * 64; // (N+1)*64 shorts (dummy)

    float* out = (float*)d_out;

    // ---- padded-CSR build: two-pass LDS-staged counting sort ----
    hipMemsetAsync(bcur, 0, 256 * sizeof(int), stream);
    binA_kernel<<<(N_EDGES + ACH - 1) / ACH, 256, 0, stream>>>(src, dst, bcur, bbuf);
    binB1_kernel<<<NBUCK, 1024, 0, stream>>>(bcur, bbuf, cnt);
    scan_part<<<NSCAN_BLK, 256, 0, stream>>>(cnt, pstart, partial);
    scan_mid<<<1, 256, 0, stream>>>(partial);
    scan_add<<<NSCAN_BLK, 256, 0, stream>>>(pstart, partial);
    binB2_kernel<<<NBUCK, 1024, 0, stream>>>(bcur, bbuf, pstart, cnt, pes, tnode);
    xprep_kernel<<<((N_NODES + 1) * 64 + 255) / 256, 256, 0, stream>>>(x, xb, hb1);

    hipMemsetAsync(psum, 0, (8192 + 128) * sizeof(float), stream);
    prep_kernel<<<1, 256, 0, stream>>>(W1a, b1a, W1b, b1b, W2a, b2a, W2b, b2b,
                                       Wab1, bab1, Wab2, bab2);

    hipMemsetAsync(aggr, 0, (size_t)N_NODES * DIM * sizeof(float), stream);
    edge_kernel<<<2048, 256, 0, stream>>>(xb, ea, We1, be1, pes, tnode, pstart, aggr);
    node_kernel<<<512, 256, 0, stream>>>(x, aggr, Wab1, bab1, h1, hb1);

    hipMemsetAsync(aggr, 0, (size_t)N_NODES * DIM * sizeof(float), stream);
    edge_kernel<<<2048, 256, 0, stream>>>(hb1, ea, We2, be2, pes, tnode, pstart, aggr);
    node_kernel<<<512, 256, 0, stream>>>(h1, aggr, Wab2, bab2, h2, hb2);

    pool_kernel<<<196, 256, 0, stream>>>(h2, batch, psum, pcnt);
    final_kernel<<<1, 256, 0, stream>>>(psum, pcnt, Wf, bfv, out);
}